// Round 13
// baseline (23916.150 us; speedup 1.0000x reference)
//
#include <hip/hip_runtime.h>
#include <hip/hip_bf16.h>

#define T_DIM 8192
#define O_DIM 1024
#define H_DIM 2048
#define G_DIM 6144   // 3*H
#define A_DIM 512
#define CHUNK 512    // steps per scan launch
#define NBLK 256     // scan blocks (1 per CU; forced by dummy LDS)

// ---- workspace layout (float offsets; total ~46.7 MB, proven safe) ----
#define OFF_GXC   0ull          // CHUNK x 3H fp32            (3,145,728 f)
#define OFF_HTAG  3145728ull    // 2 x 2048 u64 slots         (8,192 f)
#define OFF_HFP   3153920ull    // H fp32 exact carry         (2,048 f)
#define OFF_S     3155968ull    // 8192 scores fp32
#define OFF_RED   3164160ull    // max, sum (+pad)            (16 f)
#define OFF_CPART 3164176ull    // 64 x 2048 fp32             (131,072 f)
#define OFF_C     3295248ull    // 2048 fp32
#define OFF_HSBF  3297296ull    // T x H bf16                 (8,388,608 f)

__device__ __forceinline__ float bf2f(unsigned short u) {
  return __uint_as_float(((unsigned)u) << 16);
}
__device__ __forceinline__ unsigned packbf(float a, float b) {
  return (unsigned)__bfloat16_as_ushort(__float2bfloat16(a)) |
         ((unsigned)__bfloat16_as_ushort(__float2bfloat16(b)) << 16);
}

// ---------------- Phase 1: gx chunk = obs_chunk @ W_ih^T + b_ih ----------------
#define BM 64
#define BN 64
#define BK 16
__global__ __launch_bounds__(256) void gemm_gx(
    const float* __restrict__ A,   // CHUNK x O
    const float* __restrict__ B,   // 3H x O
    const float* __restrict__ bias,
    float* __restrict__ C) {       // CHUNK x 3H
  __shared__ float As[BM][BK + 1];
  __shared__ float Bs[BN][BK + 1];
  const int bm = blockIdx.x * BM;
  const int bn = blockIdx.y * BN;
  const int tid = threadIdx.x;
  const int tr = tid / 16, tc = tid % 16;
  float acc[4][4] = {};
  for (int k0 = 0; k0 < O_DIM; k0 += BK) {
    for (int i = tid; i < BM * BK; i += 256) {
      int r = i / BK, c = i % BK;
      As[r][c] = A[(size_t)(bm + r) * O_DIM + k0 + c];
    }
    for (int i = tid; i < BN * BK; i += 256) {
      int r = i / BK, c = i % BK;
      Bs[r][c] = B[(size_t)(bn + r) * O_DIM + k0 + c];
    }
    __syncthreads();
#pragma unroll
    for (int kk = 0; kk < BK; ++kk) {
      float a[4], b[4];
#pragma unroll
      for (int i = 0; i < 4; ++i) a[i] = As[tr * 4 + i][kk];
#pragma unroll
      for (int j = 0; j < 4; ++j) b[j] = Bs[tc * 4 + j][kk];
#pragma unroll
      for (int i = 0; i < 4; ++i)
#pragma unroll
        for (int j = 0; j < 4; ++j) acc[i][j] += a[i] * b[j];
    }
    __syncthreads();
  }
#pragma unroll
  for (int i = 0; i < 4; ++i)
#pragma unroll
    for (int j = 0; j < 4; ++j) {
      int r = bm + tr * 4 + i, cc = bn + tc * 4 + j;
      C[(size_t)r * G_DIM + cc] = acc[i][j] + bias[cc];
    }
}

// unpack-and-FMA one packed-bf16 uint4 (8 cols) against two staged float4s
#define DOTQ(Q, ACC)                                                  \
  do {                                                                \
    ACC += __uint_as_float((Q).x << 16)          * ha.x               \
         + __uint_as_float((Q).x & 0xffff0000u)  * ha.y               \
         + __uint_as_float((Q).y << 16)          * ha.z               \
         + __uint_as_float((Q).y & 0xffff0000u)  * ha.w               \
         + __uint_as_float((Q).z << 16)          * hb.x               \
         + __uint_as_float((Q).z & 0xffff0000u)  * hb.y               \
         + __uint_as_float((Q).w << 16)          * hb.z               \
         + __uint_as_float((Q).w & 0xffff0000u)  * hb.w;              \
  } while (0)

// ---------------- Phase 2: persistent GRU scan -------------------------------
// r12 champion + TWO coupled changes on the step critical path:
//  (1) bf16-PAIR exchange: u64 word = {bf16 h[2w], bf16 h[2w+1] | u32 tag};
//      1024 words in 2048 padded slots (each block's 4 words + 4 dummies own an
//      exclusive 64B line -> one full-line publish, r11-style). Exchange halves
//      to 8KB; poll = 2 words/thread. Own-unit carry stays EXACT fp32 in hreg
//      (reloaded per chunk from hfp side buffer) -> only cross-unit dot inputs
//      are bf16 (r2-proven numerics).
//  (2) half-pipelined poll->FMA: stage+FMA cols [0,1024) while word 1's line
//      is still in flight -> overlaps ~0.4us of dot work with arrival tail.
__global__ __launch_bounds__(512, 2) void scan_chunk(
    const float* __restrict__ W_hh,        // 3H x H fp32
    const float* __restrict__ b_hh,        // 3H
    const float* __restrict__ gxc,         // CHUNK x 3H
    unsigned long long* __restrict__ htag, // 2 x 2048 slots
    float* __restrict__ hfp,               // H fp32 exact carry
    unsigned short* __restrict__ hsbf16,   // T x H bf16
    int t0, int nsteps) {
  __shared__ char smem[98304];             // forces 1 block/CU
  float* hlbuf0 = (float*)smem;                      // H_DIM floats
  float* hlbuf1 = (float*)(smem + 8192);             // H_DIM floats
  unsigned* stage32 = (unsigned*)(smem + 16384);     // 8 u32 (bf16 bits)
  const int tid = threadIdx.x;
  const int lane = tid & 63;
  const int wv = tid >> 6;                 // wave 0..7
  const int blk = blockIdx.x;
  const int u = blk * 8 + wv;              // owned unit

  // ---- weights: fp32 load -> packed bf16 in 12 named uint4 ----
  const float4* wr0 = (const float4*)(W_hh + (size_t)(0 * H_DIM + u) * H_DIM);
  const float4* wr1 = (const float4*)(W_hh + (size_t)(1 * H_DIM + u) * H_DIM);
  const float4* wr2 = (const float4*)(W_hh + (size_t)(2 * H_DIM + u) * H_DIM);
#define LOADQ(WR, J2)                                                  \
  ({ const float4 lo = (WR)[lane + 128 * (J2)];                        \
     const float4 hi = (WR)[lane + 64 + 128 * (J2)];                   \
     uint4{packbf(lo.x, lo.y), packbf(lo.z, lo.w),                     \
           packbf(hi.x, hi.y), packbf(hi.z, hi.w)}; })
  const uint4 q00 = LOADQ(wr0, 0), q01 = LOADQ(wr0, 1),
              q02 = LOADQ(wr0, 2), q03 = LOADQ(wr0, 3);
  const uint4 q10 = LOADQ(wr1, 0), q11 = LOADQ(wr1, 1),
              q12 = LOADQ(wr1, 2), q13 = LOADQ(wr1, 3);
  const uint4 q20 = LOADQ(wr2, 0), q21 = LOADQ(wr2, 1),
              q22 = LOADQ(wr2, 2), q23 = LOADQ(wr2, 3);
#undef LOADQ

  float b0 = 0.f, b1 = 0.f, b2 = 0.f, hreg = 0.f;
  if (lane == 0) {
    b0 = b_hh[u]; b1 = b_hh[H_DIM + u]; b2 = b_hh[2 * H_DIM + u];
    hreg = hfp[u];          // exact fp32 carry across chunk boundary
  }

  // poll slots for this thread's two words (8-slot padded stride)
  const int w0 = tid, w1 = tid + 512;
  const int s0 = ((w0 >> 2) << 3) | (w0 & 3);
  const int s1 = ((w1 >> 2) << 3) | (w1 & 3);

  for (int tt = 0; tt < nsteps; ++tt) {
    const int t = t0 + tt;
    const unsigned long long* hin = htag + (size_t)(t & 1) * 2048;
    unsigned long long* hout = htag + (size_t)((t + 1) & 1) * 2048;
    float* hl = (t & 1) ? hlbuf1 : hlbuf0;   // double-buffered stage

    // gx for owner lane (issued early; hides under poll)
    float gx0 = 0.f, gx1 = 0.f, gx2 = 0.f;
    if (lane == 0) {
      const float* g = gxc + (size_t)tt * G_DIM + u;
      gx0 = g[0]; gx1 = g[H_DIM]; gx2 = g[2 * H_DIM];
    }

    // ---- poll word 0 (opportunistically load word 1) ----
    const unsigned tgt = (unsigned)t;
    unsigned long long v0, v1 = 0;
    bool ok1 = false;
    for (;;) {
      v0 = __hip_atomic_load(hin + s0, __ATOMIC_RELAXED, __HIP_MEMORY_SCOPE_AGENT);
      if (!ok1) {
        v1 = __hip_atomic_load(hin + s1, __ATOMIC_RELAXED, __HIP_MEMORY_SCOPE_AGENT);
        ok1 = ((unsigned)v1 >= tgt);
      }
      if ((unsigned)v0 >= tgt) break;
      __builtin_amdgcn_s_sleep(1);
    }
    {
      const unsigned hi = (unsigned)(v0 >> 32);
      float2 st;
      st.x = bf2f((unsigned short)(hi & 0xffff));
      st.y = bf2f((unsigned short)(hi >> 16));
      ((float2*)hl)[tid] = st;               // h[2*tid], h[2*tid+1]
    }
    __syncthreads();   // half 0 staged

    // ---- FMA cols [0,1024) while word 1's line arrives ----
    float a0 = 0.f, a1 = 0.f, a2 = 0.f;
    const float4* h4 = (const float4*)hl;
    {
      float4 ha, hb;
      ha = h4[lane +   0]; hb = h4[lane +  64];
      DOTQ(q00, a0); DOTQ(q10, a1); DOTQ(q20, a2);
      ha = h4[lane + 128]; hb = h4[lane + 192];
      DOTQ(q01, a0); DOTQ(q11, a1); DOTQ(q21, a2);
    }

    // ---- finish word 1 ----
    while (!ok1) {
      v1 = __hip_atomic_load(hin + s1, __ATOMIC_RELAXED, __HIP_MEMORY_SCOPE_AGENT);
      ok1 = ((unsigned)v1 >= tgt);
      if (!ok1) __builtin_amdgcn_s_sleep(1);
    }
    {
      const unsigned hi = (unsigned)(v1 >> 32);
      float2 st;
      st.x = bf2f((unsigned short)(hi & 0xffff));
      st.y = bf2f((unsigned short)(hi >> 16));
      ((float2*)hl)[512 + tid] = st;         // h[1024+2*tid], h[1024+2*tid+1]
    }
    __syncthreads();   // half 1 staged

    {
      float4 ha, hb;
      ha = h4[lane + 256]; hb = h4[lane + 320];
      DOTQ(q02, a0); DOTQ(q12, a1); DOTQ(q22, a2);
      ha = h4[lane + 384]; hb = h4[lane + 448];
      DOTQ(q03, a0); DOTQ(q13, a1); DOTQ(q23, a2);
    }
#pragma unroll
    for (int d = 32; d > 0; d >>= 1) {
      a0 += __shfl_xor(a0, d, 64);
      a1 += __shfl_xor(a1, d, 64);
      a2 += __shfl_xor(a2, d, 64);
    }

    // ---- gates on owner lane (exact fp32 carry); stage bf16 bits ----
    float hnew = 0.f;
    if (lane == 0) {
      const float rr = 1.f / (1.f + expf(-(gx0 + a0 + b0)));
      const float zz = 1.f / (1.f + expf(-(gx1 + a1 + b1)));
      const float nn = tanhf(gx2 + rr * (a2 + b2));
      hnew = (1.f - zz) * nn + zz * hreg;
      hreg = hnew;
      stage32[wv] = (unsigned)__bfloat16_as_ushort(__float2bfloat16(hnew));
    }
    __syncthreads();   // stage ready

    // ---- publish: one full 64B line per block (4 real + 4 dummy words) ----
    if (tid < 8) {
      const int k = tid & 3;
      const unsigned hi = stage32[2 * k] | (stage32[2 * k + 1] << 16);
      const unsigned long long word =
          ((unsigned long long)hi << 32) | (unsigned long long)(unsigned)(t + 1);
      __hip_atomic_store(hout + blk * 8 + tid, word,
                         __ATOMIC_RELAXED, __HIP_MEMORY_SCOPE_AGENT);
    }
    // ---- attention state + chunk-boundary fp32 carry (off critical path) ----
    if (lane == 0) {
      hsbf16[(size_t)t * H_DIM + u] =
          (unsigned short)__bfloat16_as_ushort(__float2bfloat16(hnew));
      if (tt == nsteps - 1) hfp[u] = hnew;
    }
  }
}

// ---------------- Phase 3a: attention scores (bf16 h_mid, fp32 h_last) --------
__global__ __launch_bounds__(256) void attn_scores(
    const unsigned short* __restrict__ hs_bf,
    const float* __restrict__ h_last,   // hfp: exact fp32 final h
    float* __restrict__ s, int n) {
  __shared__ float hl[H_DIM];
  const int tid = threadIdx.x;
  for (int i = tid; i < H_DIM; i += 256) hl[i] = h_last[i];
  __syncthreads();
  const int wave = tid >> 6, lane = tid & 63;
  const int t = blockIdx.x * 4 + wave;
  if (t >= n) return;
  const uint4* r4 = (const uint4*)(hs_bf + (size_t)t * H_DIM);
  float sum = 0.f;
#pragma unroll
  for (int u = 0; u < 4; ++u) {
    const int idx = lane + 64 * u;
    uint4 v = r4[idx];
    const float* l = hl + idx * 8;
    sum += bf2f((unsigned short)(v.x & 0xffff)) * l[0];
    sum += bf2f((unsigned short)(v.x >> 16))    * l[1];
    sum += bf2f((unsigned short)(v.y & 0xffff)) * l[2];
    sum += bf2f((unsigned short)(v.y >> 16))    * l[3];
    sum += bf2f((unsigned short)(v.z & 0xffff)) * l[4];
    sum += bf2f((unsigned short)(v.z >> 16))    * l[5];
    sum += bf2f((unsigned short)(v.w & 0xffff)) * l[6];
    sum += bf2f((unsigned short)(v.w >> 16))    * l[7];
  }
#pragma unroll
  for (int d = 32; d > 0; d >>= 1) sum += __shfl_xor(sum, d, 64);
  if (lane == 0) s[t] = sum;
}

// ---------------- Phase 3b: softmax stats ----------------
__global__ __launch_bounds__(1024) void softmax_stats(
    const float* __restrict__ s, int n, float* __restrict__ red) {
  __shared__ float buf[1024];
  const int tid = threadIdx.x;
  float m = -3.4e38f;
  for (int i = tid; i < n; i += 1024) m = fmaxf(m, s[i]);
  buf[tid] = m;
  __syncthreads();
  for (int d = 512; d > 0; d >>= 1) {
    if (tid < d) buf[tid] = fmaxf(buf[tid], buf[tid + d]);
    __syncthreads();
  }
  const float mm = buf[0];
  __syncthreads();
  float sum = 0.f;
  for (int i = tid; i < n; i += 1024) sum += expf(s[i] - mm);
  buf[tid] = sum;
  __syncthreads();
  for (int d = 512; d > 0; d >>= 1) {
    if (tid < d) buf[tid] += buf[tid + d];
    __syncthreads();
  }
  if (tid == 0) { red[0] = mm; red[1] = buf[0]; }
}

// ---------------- Phase 3c: weighted sum partials (bf16 h_mid) ----------------
__global__ __launch_bounds__(256) void attn_wsum(
    const unsigned short* __restrict__ hs_bf, const float* __restrict__ s,
    const float* __restrict__ red, float* __restrict__ c_part, int n) {
  const int tid = threadIdx.x;
  const float m = red[0];
  const float inv = 1.f / red[1];
  const int tchunk = (n + 63) / 64;
  const int t0 = blockIdx.x * tchunk;
  const int t1 = min(t0 + tchunk, n);
  float acc[8] = {};
  for (int t = t0; t < t1; ++t) {
    const float w = expf(s[t] - m) * inv;
    const uint4 v = ((const uint4*)(hs_bf + (size_t)t * H_DIM))[tid];
    acc[0] += w * bf2f((unsigned short)(v.x & 0xffff));
    acc[1] += w * bf2f((unsigned short)(v.x >> 16));
    acc[2] += w * bf2f((unsigned short)(v.y & 0xffff));
    acc[3] += w * bf2f((unsigned short)(v.y >> 16));
    acc[4] += w * bf2f((unsigned short)(v.z & 0xffff));
    acc[5] += w * bf2f((unsigned short)(v.z >> 16));
    acc[6] += w * bf2f((unsigned short)(v.w & 0xffff));
    acc[7] += w * bf2f((unsigned short)(v.w >> 16));
  }
  float* dst = c_part + (size_t)blockIdx.x * H_DIM + tid * 8;
#pragma unroll
  for (int k = 0; k < 8; ++k) dst[k] = acc[k];
}

// ---------------- Phase 3d: reduce partials ----------------
__global__ __launch_bounds__(256) void reduce_c(
    const float* __restrict__ c_part, float* __restrict__ c) {
  const int i = blockIdx.x * 256 + threadIdx.x;
  float sum = 0.f;
  for (int b = 0; b < 64; ++b) sum += c_part[(size_t)b * H_DIM + i];
  c[i] = sum;
}

// ---------------- Phase 3e: output heads ----------------
__global__ __launch_bounds__(64) void logits_kernel(
    const float* __restrict__ W_o, const float* __restrict__ b_o,
    const float* __restrict__ W_d, const float* __restrict__ b_d,
    const float* __restrict__ c, float* __restrict__ out) {
  const int j = blockIdx.x;
  const int lane = threadIdx.x;
  const float* W; const float* bb; int jj;
  if (j < A_DIM) { W = W_o; bb = b_o; jj = j; }
  else { W = W_d; bb = b_d; jj = j - A_DIM; }
  const float4* w4 = (const float4*)(W + (size_t)jj * H_DIM);
  const float4* c4 = (const float4*)c;
  float sum = 0.f;
#pragma unroll
  for (int u = 0; u < 8; ++u) {
    float4 a = w4[lane + 64 * u];
    float4 b = c4[lane + 64 * u];
    sum += a.x * b.x + a.y * b.y + a.z * b.z + a.w * b.w;
  }
#pragma unroll
  for (int d = 32; d > 0; d >>= 1) sum += __shfl_xor(sum, d, 64);
  if (lane == 0) out[j] = sum + bb[jj];
}

extern "C" void kernel_launch(void* const* d_in, const int* in_sizes, int n_in,
                              void* d_out, int out_size, void* d_ws, size_t ws_size,
                              hipStream_t stream) {
  const float* obs  = (const float*)d_in[0];
  const float* W_ih = (const float*)d_in[1];
  const float* W_hh = (const float*)d_in[2];
  const float* b_ih = (const float*)d_in[3];
  const float* b_hh = (const float*)d_in[4];
  const float* W_o  = (const float*)d_in[5];
  const float* b_o  = (const float*)d_in[6];
  const float* W_d  = (const float*)d_in[7];
  const float* b_d  = (const float*)d_in[8];
  float* out = (float*)d_out;
  float* ws = (float*)d_ws;

  float* gxc      = ws + OFF_GXC;
  unsigned long long* htag = (unsigned long long*)(ws + OFF_HTAG);
  float* hfp      = ws + OFF_HFP;
  float* s        = ws + OFF_S;
  float* red      = ws + OFF_RED;
  float* c_part   = ws + OFF_CPART;
  float* c        = ws + OFF_C;
  unsigned short* hsbf16 = (unsigned short*)(ws + OFF_HSBF);

  // slot0 = {h=0, tag=0} -> valid input for t=0; hfp=0 -> h0 carry
  hipMemsetAsync(htag, 0, 2 * 2048 * sizeof(unsigned long long), stream);
  hipMemsetAsync(hfp, 0, H_DIM * sizeof(float), stream);

  for (int ci = 0; ci < T_DIM / CHUNK; ++ci) {
    gemm_gx<<<dim3(CHUNK / BM, G_DIM / BN), 256, 0, stream>>>(
        obs + (size_t)ci * CHUNK * O_DIM, W_ih, b_ih, gxc);
    scan_chunk<<<NBLK, 512, 0, stream>>>(
        W_hh, b_hh, gxc, htag, hfp, hsbf16, ci * CHUNK, CHUNK);
  }
  // final h (fp32 exact) is in hfp

  const int n = T_DIM - 1;  // 8191 mid states
  attn_scores<<<(n + 3) / 4, 256, 0, stream>>>(hsbf16, hfp, s, n);
  softmax_stats<<<1, 1024, 0, stream>>>(s, n, red);
  attn_wsum<<<64, 256, 0, stream>>>(hsbf16, s, red, c_part, n);
  reduce_c<<<H_DIM / 256, 256, 0, stream>>>(c_part, c);
  logits_kernel<<<2 * A_DIM, 64, 0, stream>>>(W_o, b_o, W_d, b_d, c, out);
}